// Round 11
// baseline (148.169 us; speedup 1.0000x reference)
//
#include <hip/hip_runtime.h>
#include <hip/hip_bf16.h>
#include <stdint.h>

#define B_ROWS 8192
#define DIM 256
#define WPB 4        // waves per block
#define ROWS_PER_WAVE 64
#define TILE_R 256   // rows per tile (4 waves x 64)
#define TILE_C 256   // cols per tile
#define NRB 32       // 8192/256 row/col strips
#define NTRI 528     // upper-triangle tiles: 32*33/2
#define NUNITS (NTRI * 16)   // 8448 (tile-major, 16-col-phase minor)
#define NBLOCKS 512          // 8448/512 = 16.5 units/block, exact residency
#define NTILES 4             // A row-tiles per wave

typedef __bf16 bf16x8 __attribute__((ext_vector_type(8)));
typedef float f32x4 __attribute__((ext_vector_type(4)));

#if __has_builtin(__builtin_amdgcn_exp2f)
#define EXP2F(x) __builtin_amdgcn_exp2f(x)
#else
#define EXP2F(x) exp2f(x)
#endif

__device__ __forceinline__ unsigned short f2bf_rne(float f) {
    unsigned int u = __builtin_bit_cast(unsigned int, f);
    unsigned int r = (u + 0x7FFFu + ((u >> 16) & 1u)) >> 16;
    return (unsigned short)r;
}

// async global->LDS, 16B per lane; LDS dest is wave-uniform base + lane*16 (linear)
__device__ __forceinline__ void gld_lds16(const void* g, void* l) {
    __builtin_amdgcn_global_load_lds(
        (const __attribute__((address_space(1))) unsigned int*)g,
        (__attribute__((address_space(3))) unsigned int*)l, 16, 0, 0);
}

// upper-triangle decode: off(r) = 32r - r(r-1)/2; T in [0,528)
__device__ __forceinline__ void tri_decode(int T, int& r, int& c) {
    int rr = 0;
    while (32 * (rr + 1) - ((rr + 1) * rr) / 2 <= T) ++rr;
    r = rr;
    c = rr + (T - (32 * rr - (rr * (rr - 1)) / 2));
}

// ---------------- Kernel 1: L2-normalize rows -> bf16, zero accumulators + counter ----------------
__global__ __launch_bounds__(256) void normalize_k(const float* __restrict__ emb,
                                                   unsigned short* __restrict__ ebf,
                                                   float* __restrict__ Sall,
                                                   unsigned int* __restrict__ ctr) {
    const int idx = blockIdx.x * 256 + threadIdx.x;
    if (idx < 4096) {
        float4 z = {0.f, 0.f, 0.f, 0.f};
        reinterpret_cast<float4*>(Sall)[idx] = z;  // zeroes Sall+Spos (16384 floats)
    }
    if (idx == 0) *ctr = 0u;
    const int row = blockIdx.x * 4 + (threadIdx.x >> 6);
    const int lane = threadIdx.x & 63;  // 4 floats each covers DIM=256
    const float4 v = reinterpret_cast<const float4*>(emb + (size_t)row * DIM)[lane];
    float ss = v.x * v.x + v.y * v.y + v.z * v.z + v.w * v.w;
    #pragma unroll
    for (int off = 32; off; off >>= 1) ss += __shfl_xor(ss, off);
    const float scale = 1.0f / fmaxf(sqrtf(ss), 1e-12f);
    ushort4 o;
    o.x = f2bf_rne(v.x * scale);
    o.y = f2bf_rne(v.y * scale);
    o.z = f2bf_rne(v.z * scale);
    o.w = f2bf_rne(v.w * scale);
    reinterpret_cast<ushort4*>(ebf + (size_t)row * DIM)[lane] = o;
}

// ---------------- Kernel 2: SYMMETRIC sim + masked exp-sum + fused finalize ----------------
// S = E E^T is symmetric: exp(S_ij) feeds row i AND row j. Compute only upper-
// triangle 256x256 tiles (528 of 1024) -> ~half the MFMA/staging/exp work.
//  - i-side: per-wave register sums (proven epilogue), flushed per row-strip.
//  - j-side (off-diag tiles only): same ex values summed over the tile's row dim
//    (shuffle across quads) -> one atomic per column per wave-phase.
//  - Diagonal tiles: i-side only (tile contains both (i,j),(j,i)); existing
//    per-wave diag masking unchanged.
// Scheduling: flatten (tile,phase) -> 8448 units, tile-major; block b takes the
// contiguous range [16.5b, 16.5(b+1)) -> 16-17 units (+-3%), grid=512 = exact
// 2-blocks/CU residency, no tail quantization. A-fragments reload only on
// row-strip change (<=3x/block). All micro-structure (fragments, gld_lds staging
// w/ pre-swizzled source, double buffer, barrier) identical to the 51us kernel.
// Finalize fused via last-block counter (R9-validated; + missing pre-ctr barrier).
__global__ __launch_bounds__(256, 2) void sim_k(const unsigned short* __restrict__ ebf,
                                                const int* __restrict__ labels,
                                                float* __restrict__ Sall,
                                                float* __restrict__ Spos,
                                                unsigned int* __restrict__ ctr,
                                                float* __restrict__ out) {
    // exp((dot-1)/T) = exp2((dot-1) * INV_T*log2e)
    constexpr float K2 = 14.285714285714286f * 1.4426950408889634f;  // 20.60993
    __shared__ __align__(16) unsigned char bufs[2][8192];            // 16 KB
    __shared__ int lastblk;
    __shared__ float fsum[WPB];
    __shared__ int fcnt[WPB];

    const int tid  = threadIdx.x;
    const int wave = tid >> 6;
    const int lane = tid & 63;
    const int col  = lane & 15;
    const int quad = lane >> 4;
    const int lo   = lane & 31;
    const int hi   = lane >> 5;

    const int b  = blockIdx.x;
    const int u0 = b * 16 + (b >> 1);               // floor(16.5*b)
    const int u1 = (b + 1) * 16 + ((b + 1) >> 1);   // floor(16.5*(b+1))

    // ---- Per-lane pre-swizzled global source offsets (R6-proven) ----
    // Wave w stages LDS bytes [w*2048 + i*1024), i=0,1: rows rr = 4w + 2i + hi of
    // the 16-row tile; lane fetches global chunk (lo^rr)&31 of row rr (linear LDS).
    int voff[2];
    #pragma unroll
    for (int i = 0; i < 2; ++i) {
        const int rr = 4 * wave + 2 * i + hi;
        voff[i] = rr * 512 + ((lo ^ rr) & 31) * 16;
    }
    const int ldst0 = wave * 2048;

    bf16x8 afrag[NTILES][8];
    int li[NTILES][4];
    float s_all[NTILES][4] = {};
    float s_pos[NTILES][4] = {};

    auto load_A = [&](int ib) {
        #pragma unroll
        for (int t = 0; t < NTILES; ++t) {
            const int arow = ib + t * 16 + col;
            const uint4* ap = reinterpret_cast<const uint4*>(ebf) + (size_t)arow * 32 + quad;
            #pragma unroll
            for (int kk = 0; kk < 8; ++kk)
                afrag[t][kk] = __builtin_bit_cast(bf16x8, ap[kk * 4]);
            #pragma unroll
            for (int r2 = 0; r2 < 4; ++r2)
                li[t][r2] = labels[ib + t * 16 + quad * 4 + r2];
        }
    };

    auto flush_i = [&](int ib) {
        #pragma unroll
        for (int t = 0; t < NTILES; ++t) {
            #pragma unroll
            for (int r2 = 0; r2 < 4; ++r2) {
                float a = s_all[t][r2];
                float pp = s_pos[t][r2];
                #pragma unroll
                for (int off = 1; off < 16; off <<= 1) {
                    a += __shfl_xor(a, off);
                    pp += __shfl_xor(pp, off);
                }
                if (col == 0) {
                    const int irow = ib + t * 16 + quad * 4 + r2;
                    atomicAdd(&Sall[irow], a);
                    atomicAdd(&Spos[irow], pp);
                }
                s_all[t][r2] = 0.0f;
                s_pos[t][r2] = 0.0f;
            }
        }
    };

    // ---- Prologue: stage unit u0 into bufs[0]; prefetch its column label ----
    int ljc, ljn = 0;
    {
        const int t0 = u0 >> 4, p0 = u0 & 15;
        int r0, c0;
        tri_decode(t0, r0, c0);
        const char* gT = reinterpret_cast<const char*>(ebf) +
                         (size_t)c0 * 256 * 512 + (size_t)p0 * 8192;
        gld_lds16(gT + voff[0], bufs[0] + ldst0);
        gld_lds16(gT + voff[1], bufs[0] + ldst0 + 1024);
        ljc = labels[c0 * 256 + p0 * 16 + col];
    }
    __syncthreads();

    int cur_r = -1;
    int my_ibase = 0;

    #pragma unroll 1
    for (int u = u0; u < u1; ++u) {
        const int k = u - u0;
        const int tile = u >> 4, ph = u & 15;
        int r, c;
        tri_decode(tile, r, c);
        const int j0 = c * 256;

        if (r != cur_r) {
            if (cur_r >= 0) flush_i(my_ibase);
            my_ibase = r * 256 + wave * ROWS_PER_WAVE;
            load_A(my_ibase);
            cur_r = r;
        }

        // stage next unit (tile-agnostic formula) + prefetch its column label
        if (u + 1 < u1) {
            const int un = u + 1, tn = un >> 4, pn = un & 15;
            int rn, cn;
            tri_decode(tn, rn, cn);
            const char* gT = reinterpret_cast<const char*>(ebf) +
                             (size_t)cn * 256 * 512 + (size_t)pn * 8192;
            unsigned char* bw = bufs[(k + 1) & 1];
            gld_lds16(gT + voff[0], bw + ldst0);
            gld_lds16(gT + voff[1], bw + ldst0 + 1024);
            ljn = labels[cn * 256 + pn * 16 + col];
        }

        // ---- MFMA: 8 ds_read + 32 MFMA (4 independent chains) ----
        const unsigned char* bufR = bufs[k & 1];
        f32x4 acc[NTILES];
        #pragma unroll
        for (int t = 0; t < NTILES; ++t) acc[t] = (f32x4){0.f, 0.f, 0.f, 0.f};
        __builtin_amdgcn_s_setprio(1);
        #pragma unroll
        for (int kk = 0; kk < 8; ++kk) {
            const int cc = kk * 4 + quad;
            const bf16x8 bfrag = *reinterpret_cast<const bf16x8*>(
                &bufR[col * 512 + ((cc ^ col) & 31) * 16]);
            #pragma unroll
            for (int t = 0; t < NTILES; ++t)
                acc[t] = __builtin_amdgcn_mfma_f32_16x16x32_bf16(afrag[t][kk], bfrag, acc[t], 0, 0, 0);
        }
        __builtin_amdgcn_s_setprio(0);

        // ---- Epilogue. D[row = quad*4+r2][col]; jcol = j0 + ph*16 + col ----
        const int jcol = j0 + ph * 16 + col;
        if (c > r) {
            // off-diagonal tile: strips disjoint, no diag masking; i-side + j-side
            float jall = 0.0f, jpos = 0.0f;
            #pragma unroll
            for (int t = 0; t < NTILES; ++t) {
                #pragma unroll
                for (int r2 = 0; r2 < 4; ++r2) {
                    const float ex = EXP2F(fmaf(acc[t][r2], K2, -K2));
                    const bool m = (ljc == li[t][r2]);
                    s_all[t][r2] += ex;
                    s_pos[t][r2] += m ? ex : 0.0f;
                    jall += ex;
                    jpos += m ? ex : 0.0f;
                }
            }
            // reduce over the tile's 64 rows: sum across the 4 quads of this col
            jall += __shfl_xor(jall, 16);
            jall += __shfl_xor(jall, 32);
            jpos += __shfl_xor(jpos, 16);
            jpos += __shfl_xor(jpos, 32);
            if (quad == 0) {
                atomicAdd(&Sall[jcol], jall);
                atomicAdd(&Spos[jcol], jpos);
            }
        } else {
            // diagonal tile: i-side only (tile holds both (i,j) and (j,i))
            const int strip = j0 + ph * 16;
            const bool diag_possible = (strip < my_ibase + ROWS_PER_WAVE) && (my_ibase < strip + 16);
            if (!diag_possible) {
                #pragma unroll
                for (int t = 0; t < NTILES; ++t) {
                    #pragma unroll
                    for (int r2 = 0; r2 < 4; ++r2) {
                        const float ex = EXP2F(fmaf(acc[t][r2], K2, -K2));
                        s_all[t][r2] += ex;
                        s_pos[t][r2] += (ljc == li[t][r2]) ? ex : 0.0f;
                    }
                }
            } else {
                #pragma unroll
                for (int t = 0; t < NTILES; ++t) {
                    #pragma unroll
                    for (int r2 = 0; r2 < 4; ++r2) {
                        const int irow = my_ibase + t * 16 + quad * 4 + r2;
                        const float ex = EXP2F(fmaf(acc[t][r2], K2, -K2));
                        const bool valid = (jcol != irow);
                        const bool pos = valid && (ljc == li[t][r2]);
                        s_all[t][r2] += valid ? ex : 0.0f;
                        s_pos[t][r2] += pos ? ex : 0.0f;
                    }
                }
            }
        }

        ljc = ljn;
        __syncthreads();
    }
    flush_i(my_ibase);

    // ---- Fused finalize: last block computes the mean loss ----
    __threadfence();
    __syncthreads();                     // all waves' atomics issued+fenced before ctr bump
    if (tid == 0) {
        const unsigned prev = atomicAdd(ctr, 1u);
        lastblk = (prev == (unsigned)(gridDim.x - 1)) ? 1 : 0;
    }
    __syncthreads();
    if (lastblk) {
        __threadfence();  // acquire side
        float sum = 0.0f;
        int cnt = 0;
        #pragma unroll 4
        for (int i = tid; i < B_ROWS; i += 256) {
            const float sp = __hip_atomic_load(&Spos[i], __ATOMIC_RELAXED, __HIP_MEMORY_SCOPE_AGENT);
            const float sa = __hip_atomic_load(&Sall[i], __ATOMIC_RELAXED, __HIP_MEMORY_SCOPE_AGENT);
            if (sp > 0.0f) {
                sum += __logf(__fdividef(sa, sp));
                ++cnt;
            }
        }
        #pragma unroll
        for (int off = 32; off; off >>= 1) {
            sum += __shfl_xor(sum, off);
            cnt += __shfl_xor(cnt, off);
        }
        if (lane == 0) { fsum[wave] = sum; fcnt[wave] = cnt; }
        __syncthreads();
        if (tid == 0) {
            float s = 0.0f;
            int c = 0;
            #pragma unroll
            for (int w = 0; w < WPB; ++w) { s += fsum[w]; c += fcnt[w]; }
            out[0] = (c > 0) ? s / (float)c : 0.0f;
        }
    }
}

extern "C" void kernel_launch(void* const* d_in, const int* in_sizes, int n_in,
                              void* d_out, int out_size, void* d_ws, size_t ws_size,
                              hipStream_t stream) {
    const float* emb   = (const float*)d_in[0];
    const int* labels  = (const int*)d_in[1];
    float* out         = (float*)d_out;

    unsigned short* ebf = (unsigned short*)d_ws;                       // 4 MB bf16 normalized
    float* Sall = (float*)((char*)d_ws + (size_t)B_ROWS * DIM * 2);    // 32 KB
    float* Spos = Sall + B_ROWS;                                       // 32 KB
    unsigned int* ctr = (unsigned int*)(Spos + B_ROWS);                // 4 B

    normalize_k<<<B_ROWS / 4, 256, 0, stream>>>(emb, ebf, Sall, ctr);
    sim_k<<<NBLOCKS, 256, 0, stream>>>(ebf, labels, Sall, Spos, ctr, out);
}

// Round 13
// 142.895 us; speedup vs baseline: 1.0369x; 1.0369x over previous
//
#include <hip/hip_runtime.h>
#include <hip/hip_bf16.h>
#include <stdint.h>

#define B_ROWS 8192
#define DIM 256
#define JCHUNK 512
#define WPB 4   // waves per block
#define ROWS_PER_WAVE 64
#define ROWS_PER_BLOCK (WPB * ROWS_PER_WAVE)  // 256
#define NT (JCHUNK / 16)                      // 32 j-tiles per block
#define NTILES 4                              // A row-tiles per wave

typedef __bf16 bf16x8 __attribute__((ext_vector_type(8)));
typedef float f32x4 __attribute__((ext_vector_type(4)));

#if __has_builtin(__builtin_amdgcn_exp2f)
#define EXP2F(x) __builtin_amdgcn_exp2f(x)
#else
#define EXP2F(x) exp2f(x)
#endif

__device__ __forceinline__ unsigned short f2bf_rne(float f) {
    unsigned int u = __builtin_bit_cast(unsigned int, f);
    unsigned int r = (u + 0x7FFFu + ((u >> 16) & 1u)) >> 16;
    return (unsigned short)r;
}

// async global->LDS, 16B per lane; LDS dest is wave-uniform base + lane*16 (linear)
__device__ __forceinline__ void gld_lds16(const void* g, void* l) {
    __builtin_amdgcn_global_load_lds(
        (const __attribute__((address_space(1))) unsigned int*)g,
        (__attribute__((address_space(3))) unsigned int*)l, 16, 0, 0);
}

// ---------------- Kernel 1: L2-normalize rows -> bf16, zero accumulators + counter ----------------
__global__ __launch_bounds__(256) void normalize_k(const float* __restrict__ emb,
                                                   unsigned short* __restrict__ ebf,
                                                   float* __restrict__ Sall,
                                                   unsigned int* __restrict__ ctr) {
    const int idx = blockIdx.x * 256 + threadIdx.x;
    if (idx < 4096) {
        float4 z = {0.f, 0.f, 0.f, 0.f};
        reinterpret_cast<float4*>(Sall)[idx] = z;  // zeroes Sall+Spos (16384 floats)
    }
    if (idx == 0) *ctr = 0u;
    const int row = blockIdx.x * 4 + (threadIdx.x >> 6);
    const int lane = threadIdx.x & 63;  // 4 floats each covers DIM=256
    const float4 v = reinterpret_cast<const float4*>(emb + (size_t)row * DIM)[lane];
    float ss = v.x * v.x + v.y * v.y + v.z * v.z + v.w * v.w;
    #pragma unroll
    for (int off = 32; off; off >>= 1) ss += __shfl_xor(ss, off);
    const float scale = 1.0f / fmaxf(sqrtf(ss), 1e-12f);
    ushort4 o;
    o.x = f2bf_rne(v.x * scale);
    o.y = f2bf_rne(v.y * scale);
    o.z = f2bf_rne(v.z * scale);
    o.w = f2bf_rne(v.w * scale);
    reinterpret_cast<ushort4*>(ebf + (size_t)row * DIM)[lane] = o;
}

// ---------------- Kernel 2: fused sim + masked exp-sum + FUSED FINALIZE ----------------
// Main loop is byte-identical to the proven 50.9us R10 kernel (64 rows/wave, 4
// A-tiles register-resident, cooperative gld_lds staging w/ pre-swizzled source,
// double LDS buffer, pipelined epilogue). R11 evidence: moving finalize out of its
// own 1-block kernel (HBM-latency-bound on a cold 64KB read + one launch) into the
// last sim_k block (Sall/Spos L2-hot) saves ~8-10us of wall. Counter pattern
// R9/R11-validated (threadfence + pre-ctr barrier; ctr zeroed in normalize_k).
__global__ __launch_bounds__(256, 2) void sim_k(const unsigned short* __restrict__ ebf,
                                                const int* __restrict__ labels,
                                                float* __restrict__ Sall,
                                                float* __restrict__ Spos,
                                                unsigned int* __restrict__ ctr,
                                                float* __restrict__ out) {
    // exp((dot-1)/T) = exp2((dot-1) * INV_T*log2e)
    constexpr float K2 = 14.285714285714286f * 1.4426950408889634f;  // 20.60993
    __shared__ __align__(16) unsigned char bufs[2][8192];            // 16 KB
    __shared__ int lds_lab[JCHUNK];
    __shared__ int lastblk;
    __shared__ float fsum[WPB];
    __shared__ int fcnt[WPB];

    const int tid  = threadIdx.x;
    const int wave = tid >> 6;
    const int lane = tid & 63;
    const int col  = lane & 15;
    const int quad = lane >> 4;
    const int lo   = lane & 31;
    const int hi   = lane >> 5;

    const int rowblk = blockIdx.x >> 4;            // 0..31
    const int jblk   = blockIdx.x & 15;            // 0..15
    const int i_base = rowblk * ROWS_PER_BLOCK + wave * ROWS_PER_WAVE;
    const int j0     = jblk * JCHUNK;

    // ---- Preload A-fragments (4 tiles x 8 K-steps) + row labels ----
    // lane L holds A[row = L&15][k = kk*32 + (L>>4)*8 + 0..7]
    bf16x8 afrag[NTILES][8];
    int li[NTILES][4];
    #pragma unroll
    for (int t = 0; t < NTILES; ++t) {
        const int arow = i_base + t * 16 + col;
        const uint4* ap = reinterpret_cast<const uint4*>(ebf) + (size_t)arow * 32 + quad;
        #pragma unroll
        for (int kk = 0; kk < 8; ++kk)
            afrag[t][kk] = __builtin_bit_cast(bf16x8, ap[kk * 4]);
        #pragma unroll
        for (int r = 0; r < 4; ++r)
            li[t][r] = labels[i_base + t * 16 + quad * 4 + r];
    }

    // ---- Per-lane pre-swizzled global source offsets (R6-proven) ----
    int voff[2];
    #pragma unroll
    for (int i = 0; i < 2; ++i) {
        const int r = 4 * wave + 2 * i + hi;
        voff[i] = r * 512 + ((lo ^ r) & 31) * 16;
    }
    const int ldst0 = wave * 2048;

    const char* gBase = reinterpret_cast<const char*>(ebf) + (size_t)j0 * 512;

    // ---- Prologue: labels -> LDS; stage tile 0 into bufs[0] ----
    lds_lab[tid] = labels[j0 + tid];
    lds_lab[256 + tid] = labels[j0 + 256 + tid];
    gld_lds16(gBase + voff[0], bufs[0] + ldst0);
    gld_lds16(gBase + voff[1], bufs[0] + ldst0 + 1024);
    __syncthreads();

    float s_all[NTILES][4] = {};
    float s_pos[NTILES][4] = {};
    f32x4 accA[NTILES], accB[NTILES];

    auto do_mfma = [&](f32x4* acc, const unsigned char* bufR) {
        #pragma unroll
        for (int t = 0; t < NTILES; ++t) acc[t] = (f32x4){0.f, 0.f, 0.f, 0.f};
        __builtin_amdgcn_s_setprio(1);
        #pragma unroll
        for (int kk = 0; kk < 8; ++kk) {
            const int c = kk * 4 + quad;
            const bf16x8 bfrag = *reinterpret_cast<const bf16x8*>(
                &bufR[col * 512 + ((c ^ col) & 31) * 16]);
            #pragma unroll
            for (int t = 0; t < NTILES; ++t)
                acc[t] = __builtin_amdgcn_mfma_f32_16x16x32_bf16(afrag[t][kk], bfrag, acc[t], 0, 0, 0);
        }
        __builtin_amdgcn_s_setprio(0);
    };

    auto do_epi = [&](const f32x4* acc, int jt) {
        const int lj = lds_lab[jt * 16 + col];
        const int jcol = j0 + jt * 16 + col;
        const int jt16 = j0 + jt * 16;
        const bool diag_possible = (jt16 < i_base + ROWS_PER_WAVE) && (i_base < jt16 + 16);
        if (!diag_possible) {
            #pragma unroll
            for (int t = 0; t < NTILES; ++t) {
                #pragma unroll
                for (int r = 0; r < 4; ++r) {
                    const float ex = EXP2F(fmaf(acc[t][r], K2, -K2));
                    s_all[t][r] += ex;
                    s_pos[t][r] += (lj == li[t][r]) ? ex : 0.0f;
                }
            }
        } else {
            #pragma unroll
            for (int t = 0; t < NTILES; ++t) {
                #pragma unroll
                for (int r = 0; r < 4; ++r) {
                    const int irow = i_base + t * 16 + quad * 4 + r;
                    const float ex = EXP2F(fmaf(acc[t][r], K2, -K2));
                    const bool valid = (jcol != irow);
                    const bool pos = valid && (lj == li[t][r]);
                    s_all[t][r] += valid ? ex : 0.0f;
                    s_pos[t][r] += pos ? ex : 0.0f;
                }
            }
        }
    };

    #pragma unroll 1
    for (int m = 0; m < NT / 2; ++m) {
        const int jt0 = 2 * m, jt1 = 2 * m + 1;

        // ---- phase jt0: read bufs[0], stage jt0+1 into bufs[1] ----
        {
            const char* gT = gBase + (size_t)(jt0 + 1) * 8192;   // jt0+1 <= 31 always
            gld_lds16(gT + voff[0], bufs[1] + ldst0);
            gld_lds16(gT + voff[1], bufs[1] + ldst0 + 1024);
        }
        do_mfma(accA, bufs[0]);
        if (m > 0) do_epi(accB, jt0 - 1);   // overlap: exp(jt0-1) under MFMA(jt0) drain
        __syncthreads();

        // ---- phase jt1: read bufs[1], stage jt1+1 into bufs[0] ----
        if (jt1 + 1 < NT) {
            const char* gT = gBase + (size_t)(jt1 + 1) * 8192;
            gld_lds16(gT + voff[0], bufs[0] + ldst0);
            gld_lds16(gT + voff[1], bufs[0] + ldst0 + 1024);
        }
        do_mfma(accB, bufs[1]);
        do_epi(accA, jt0);                  // overlap: exp(jt0) under MFMA(jt1) drain
        __syncthreads();
    }
    do_epi(accB, NT - 1);                   // tail epilogue

    // Reduce over the 16 column-lanes within each quad, then one atomic per row.
    #pragma unroll
    for (int t = 0; t < NTILES; ++t) {
        #pragma unroll
        for (int r = 0; r < 4; ++r) {
            float a = s_all[t][r];
            float pp = s_pos[t][r];
            #pragma unroll
            for (int off = 1; off < 16; off <<= 1) {
                a += __shfl_xor(a, off);
                pp += __shfl_xor(pp, off);
            }
            if (col == 0) {
                const int irow = i_base + t * 16 + quad * 4 + r;
                atomicAdd(&Sall[irow], a);
                atomicAdd(&Spos[irow], pp);
            }
        }
    }

    // ---- Fused finalize: last block computes the mean loss (R9/R11-validated) ----
    __threadfence();
    __syncthreads();                     // all waves' atomics issued+fenced before ctr bump
    if (tid == 0) {
        const unsigned prev = atomicAdd(ctr, 1u);
        lastblk = (prev == (unsigned)(gridDim.x - 1)) ? 1 : 0;
    }
    __syncthreads();
    if (lastblk) {
        __threadfence();  // acquire side
        float sum = 0.0f;
        int cnt = 0;
        #pragma unroll 4
        for (int i = tid; i < B_ROWS; i += 256) {
            const float sp = __hip_atomic_load(&Spos[i], __ATOMIC_RELAXED, __HIP_MEMORY_SCOPE_AGENT);
            const float sa = __hip_atomic_load(&Sall[i], __ATOMIC_RELAXED, __HIP_MEMORY_SCOPE_AGENT);
            if (sp > 0.0f) {
                sum += __logf(__fdividef(sa, sp));
                ++cnt;
            }
        }
        #pragma unroll
        for (int off = 32; off; off >>= 1) {
            sum += __shfl_xor(sum, off);
            cnt += __shfl_xor(cnt, off);
        }
        if (lane == 0) { fsum[wave] = sum; fcnt[wave] = cnt; }
        __syncthreads();
        if (tid == 0) {
            float s = 0.0f;
            int c = 0;
            #pragma unroll
            for (int w = 0; w < WPB; ++w) { s += fsum[w]; c += fcnt[w]; }
            out[0] = (c > 0) ? s / (float)c : 0.0f;
        }
    }
}

extern "C" void kernel_launch(void* const* d_in, const int* in_sizes, int n_in,
                              void* d_out, int out_size, void* d_ws, size_t ws_size,
                              hipStream_t stream) {
    const float* emb   = (const float*)d_in[0];
    const int* labels  = (const int*)d_in[1];
    float* out         = (float*)d_out;

    unsigned short* ebf = (unsigned short*)d_ws;                       // 4 MB bf16 normalized
    float* Sall = (float*)((char*)d_ws + (size_t)B_ROWS * DIM * 2);    // 32 KB
    float* Spos = Sall + B_ROWS;                                       // 32 KB
    unsigned int* ctr = (unsigned int*)(Spos + B_ROWS);                // 4 B

    normalize_k<<<B_ROWS / 4, 256, 0, stream>>>(emb, ebf, Sall, ctr);

    dim3 grid((B_ROWS / ROWS_PER_BLOCK) * (B_ROWS / JCHUNK));          // 32*16 = 512
    sim_k<<<grid, 256, 0, stream>>>(ebf, labels, Sall, Spos, ctr, out);
}

// Round 14
// 120.569 us; speedup vs baseline: 1.2289x; 1.1852x over previous
//
#include <hip/hip_runtime.h>
#include <hip/hip_bf16.h>
#include <stdint.h>

#define B_ROWS 8192
#define DIM 256
#define JCHUNK 512
#define WPB 4   // waves per block
#define ROWS_PER_WAVE 64
#define ROWS_PER_BLOCK (WPB * ROWS_PER_WAVE)  // 256
#define NT (JCHUNK / 16)                      // 32 j-tiles per block
#define NTILES 4                              // A row-tiles per wave

typedef __bf16 bf16x8 __attribute__((ext_vector_type(8)));
typedef float f32x4 __attribute__((ext_vector_type(4)));

#if __has_builtin(__builtin_amdgcn_exp2f)
#define EXP2F(x) __builtin_amdgcn_exp2f(x)
#else
#define EXP2F(x) exp2f(x)
#endif

__device__ __forceinline__ unsigned short f2bf_rne(float f) {
    unsigned int u = __builtin_bit_cast(unsigned int, f);
    unsigned int r = (u + 0x7FFFu + ((u >> 16) & 1u)) >> 16;
    return (unsigned short)r;
}

// async global->LDS, 16B per lane; LDS dest is wave-uniform base + lane*16 (linear)
__device__ __forceinline__ void gld_lds16(const void* g, void* l) {
    __builtin_amdgcn_global_load_lds(
        (const __attribute__((address_space(1))) unsigned int*)g,
        (__attribute__((address_space(3))) unsigned int*)l, 16, 0, 0);
}

// ---------------- Kernel 1: L2-normalize rows -> bf16, zero accumulators + counter ----------------
__global__ __launch_bounds__(256) void normalize_k(const float* __restrict__ emb,
                                                   unsigned short* __restrict__ ebf,
                                                   float* __restrict__ Sall,
                                                   unsigned int* __restrict__ ctr) {
    const int idx = blockIdx.x * 256 + threadIdx.x;
    if (idx < 4096) {
        float4 z = {0.f, 0.f, 0.f, 0.f};
        reinterpret_cast<float4*>(Sall)[idx] = z;  // zeroes Sall+Spos (16384 floats)
    }
    if (idx == 0) *ctr = 0u;
    const int row = blockIdx.x * 4 + (threadIdx.x >> 6);
    const int lane = threadIdx.x & 63;  // 4 floats each covers DIM=256
    const float4 v = reinterpret_cast<const float4*>(emb + (size_t)row * DIM)[lane];
    float ss = v.x * v.x + v.y * v.y + v.z * v.z + v.w * v.w;
    #pragma unroll
    for (int off = 32; off; off >>= 1) ss += __shfl_xor(ss, off);
    const float scale = 1.0f / fmaxf(sqrtf(ss), 1e-12f);
    ushort4 o;
    o.x = f2bf_rne(v.x * scale);
    o.y = f2bf_rne(v.y * scale);
    o.z = f2bf_rne(v.z * scale);
    o.w = f2bf_rne(v.w * scale);
    reinterpret_cast<ushort4*>(ebf + (size_t)row * DIM)[lane] = o;
}

// ---------------- Kernel 2: fused sim + masked exp-sum + FENCE-FREE fused finalize ----------------
// Main loop byte-identical to the proven 50.9us R10 kernel. R13 lesson: per-block
// __threadfence() (L2 writeback+invalidate on multi-XCD gfx950) thrashed L2 for all
// concurrent blocks (sim_k 51->89us, WRITE_SIZE +0.5MB of writebacks). Fence-free
// replacement, no cache-wide operations:
//  - producer: atomicAdds are device-scope RMWs at the coherence point; a plain
//    s_waitcnt vmcnt(0) before the ctr bump guarantees completion (no wbl2/inv).
//  - consumer (last block): reads Sall/Spos via atomicAdd(p, 0.0f) -- RMW-reads
//    serialize against the producers' RMWs at the coherence point, immune to any
//    stale L1/L2 copy. ~16k RMWs from 4 waves ~= 2-4us, cheaper than a launch.
__global__ __launch_bounds__(256, 2) void sim_k(const unsigned short* __restrict__ ebf,
                                                const int* __restrict__ labels,
                                                float* __restrict__ Sall,
                                                float* __restrict__ Spos,
                                                unsigned int* __restrict__ ctr,
                                                float* __restrict__ out) {
    // exp((dot-1)/T) = exp2((dot-1) * INV_T*log2e)
    constexpr float K2 = 14.285714285714286f * 1.4426950408889634f;  // 20.60993
    __shared__ __align__(16) unsigned char bufs[2][8192];            // 16 KB
    __shared__ int lds_lab[JCHUNK];
    __shared__ int lastblk;
    __shared__ float fsum[WPB];
    __shared__ int fcnt[WPB];

    const int tid  = threadIdx.x;
    const int wave = tid >> 6;
    const int lane = tid & 63;
    const int col  = lane & 15;
    const int quad = lane >> 4;
    const int lo   = lane & 31;
    const int hi   = lane >> 5;

    const int rowblk = blockIdx.x >> 4;            // 0..31
    const int jblk   = blockIdx.x & 15;            // 0..15
    const int i_base = rowblk * ROWS_PER_BLOCK + wave * ROWS_PER_WAVE;
    const int j0     = jblk * JCHUNK;

    // ---- Preload A-fragments (4 tiles x 8 K-steps) + row labels ----
    // lane L holds A[row = L&15][k = kk*32 + (L>>4)*8 + 0..7]
    bf16x8 afrag[NTILES][8];
    int li[NTILES][4];
    #pragma unroll
    for (int t = 0; t < NTILES; ++t) {
        const int arow = i_base + t * 16 + col;
        const uint4* ap = reinterpret_cast<const uint4*>(ebf) + (size_t)arow * 32 + quad;
        #pragma unroll
        for (int kk = 0; kk < 8; ++kk)
            afrag[t][kk] = __builtin_bit_cast(bf16x8, ap[kk * 4]);
        #pragma unroll
        for (int r = 0; r < 4; ++r)
            li[t][r] = labels[i_base + t * 16 + quad * 4 + r];
    }

    // ---- Per-lane pre-swizzled global source offsets (R6-proven) ----
    int voff[2];
    #pragma unroll
    for (int i = 0; i < 2; ++i) {
        const int r = 4 * wave + 2 * i + hi;
        voff[i] = r * 512 + ((lo ^ r) & 31) * 16;
    }
    const int ldst0 = wave * 2048;

    const char* gBase = reinterpret_cast<const char*>(ebf) + (size_t)j0 * 512;

    // ---- Prologue: labels -> LDS; stage tile 0 into bufs[0] ----
    lds_lab[tid] = labels[j0 + tid];
    lds_lab[256 + tid] = labels[j0 + 256 + tid];
    gld_lds16(gBase + voff[0], bufs[0] + ldst0);
    gld_lds16(gBase + voff[1], bufs[0] + ldst0 + 1024);
    __syncthreads();

    float s_all[NTILES][4] = {};
    float s_pos[NTILES][4] = {};
    f32x4 accA[NTILES], accB[NTILES];

    auto do_mfma = [&](f32x4* acc, const unsigned char* bufR) {
        #pragma unroll
        for (int t = 0; t < NTILES; ++t) acc[t] = (f32x4){0.f, 0.f, 0.f, 0.f};
        __builtin_amdgcn_s_setprio(1);
        #pragma unroll
        for (int kk = 0; kk < 8; ++kk) {
            const int c = kk * 4 + quad;
            const bf16x8 bfrag = *reinterpret_cast<const bf16x8*>(
                &bufR[col * 512 + ((c ^ col) & 31) * 16]);
            #pragma unroll
            for (int t = 0; t < NTILES; ++t)
                acc[t] = __builtin_amdgcn_mfma_f32_16x16x32_bf16(afrag[t][kk], bfrag, acc[t], 0, 0, 0);
        }
        __builtin_amdgcn_s_setprio(0);
    };

    auto do_epi = [&](const f32x4* acc, int jt) {
        const int lj = lds_lab[jt * 16 + col];
        const int jcol = j0 + jt * 16 + col;
        const int jt16 = j0 + jt * 16;
        const bool diag_possible = (jt16 < i_base + ROWS_PER_WAVE) && (i_base < jt16 + 16);
        if (!diag_possible) {
            #pragma unroll
            for (int t = 0; t < NTILES; ++t) {
                #pragma unroll
                for (int r = 0; r < 4; ++r) {
                    const float ex = EXP2F(fmaf(acc[t][r], K2, -K2));
                    s_all[t][r] += ex;
                    s_pos[t][r] += (lj == li[t][r]) ? ex : 0.0f;
                }
            }
        } else {
            #pragma unroll
            for (int t = 0; t < NTILES; ++t) {
                #pragma unroll
                for (int r = 0; r < 4; ++r) {
                    const int irow = i_base + t * 16 + quad * 4 + r;
                    const float ex = EXP2F(fmaf(acc[t][r], K2, -K2));
                    const bool valid = (jcol != irow);
                    const bool pos = valid && (lj == li[t][r]);
                    s_all[t][r] += valid ? ex : 0.0f;
                    s_pos[t][r] += pos ? ex : 0.0f;
                }
            }
        }
    };

    #pragma unroll 1
    for (int m = 0; m < NT / 2; ++m) {
        const int jt0 = 2 * m, jt1 = 2 * m + 1;

        // ---- phase jt0: read bufs[0], stage jt0+1 into bufs[1] ----
        {
            const char* gT = gBase + (size_t)(jt0 + 1) * 8192;   // jt0+1 <= 31 always
            gld_lds16(gT + voff[0], bufs[1] + ldst0);
            gld_lds16(gT + voff[1], bufs[1] + ldst0 + 1024);
        }
        do_mfma(accA, bufs[0]);
        if (m > 0) do_epi(accB, jt0 - 1);   // overlap: exp(jt0-1) under MFMA(jt0) drain
        __syncthreads();

        // ---- phase jt1: read bufs[1], stage jt1+1 into bufs[0] ----
        if (jt1 + 1 < NT) {
            const char* gT = gBase + (size_t)(jt1 + 1) * 8192;
            gld_lds16(gT + voff[0], bufs[0] + ldst0);
            gld_lds16(gT + voff[1], bufs[0] + ldst0 + 1024);
        }
        do_mfma(accB, bufs[1]);
        do_epi(accA, jt0);                  // overlap: exp(jt0) under MFMA(jt1) drain
        __syncthreads();
    }
    do_epi(accB, NT - 1);                   // tail epilogue

    // Reduce over the 16 column-lanes within each quad, then one atomic per row.
    #pragma unroll
    for (int t = 0; t < NTILES; ++t) {
        #pragma unroll
        for (int r = 0; r < 4; ++r) {
            float a = s_all[t][r];
            float pp = s_pos[t][r];
            #pragma unroll
            for (int off = 1; off < 16; off <<= 1) {
                a += __shfl_xor(a, off);
                pp += __shfl_xor(pp, off);
            }
            if (col == 0) {
                const int irow = i_base + t * 16 + quad * 4 + r;
                atomicAdd(&Sall[irow], a);
                atomicAdd(&Spos[irow], pp);
            }
        }
    }

    // ---- Fence-free fused finalize ----
    // Producer ordering: wait for this block's atomicAdds to COMPLETE at the
    // coherence point (vmcnt covers atomics) -- no cache writeback/invalidate.
    asm volatile("s_waitcnt vmcnt(0)" ::: "memory");
    __syncthreads();
    if (tid == 0) {
        const unsigned prev = atomicAdd(ctr, 1u);   // device-scope RMW
        lastblk = (prev == (unsigned)(gridDim.x - 1)) ? 1 : 0;
    }
    __syncthreads();
    if (lastblk) {
        float sum = 0.0f;
        int cnt = 0;
        for (int i = tid; i < B_ROWS; i += 256) {
            // RMW-reads: serialized with producers' RMWs at the coherence point
            const float sp = atomicAdd(&Spos[i], 0.0f);
            const float sa = atomicAdd(&Sall[i], 0.0f);
            if (sp > 0.0f) {
                sum += __logf(__fdividef(sa, sp));
                ++cnt;
            }
        }
        #pragma unroll
        for (int off = 32; off; off >>= 1) {
            sum += __shfl_xor(sum, off);
            cnt += __shfl_xor(cnt, off);
        }
        if (lane == 0) { fsum[wave] = sum; fcnt[wave] = cnt; }
        __syncthreads();
        if (tid == 0) {
            float s = 0.0f;
            int c = 0;
            #pragma unroll
            for (int w = 0; w < WPB; ++w) { s += fsum[w]; c += fcnt[w]; }
            out[0] = (c > 0) ? s / (float)c : 0.0f;
        }
    }
}

extern "C" void kernel_launch(void* const* d_in, const int* in_sizes, int n_in,
                              void* d_out, int out_size, void* d_ws, size_t ws_size,
                              hipStream_t stream) {
    const float* emb   = (const float*)d_in[0];
    const int* labels  = (const int*)d_in[1];
    float* out         = (float*)d_out;

    unsigned short* ebf = (unsigned short*)d_ws;                       // 4 MB bf16 normalized
    float* Sall = (float*)((char*)d_ws + (size_t)B_ROWS * DIM * 2);    // 32 KB
    float* Spos = Sall + B_ROWS;                                       // 32 KB
    unsigned int* ctr = (unsigned int*)(Spos + B_ROWS);                // 4 B

    normalize_k<<<B_ROWS / 4, 256, 0, stream>>>(emb, ebf, Sall, ctr);

    dim3 grid((B_ROWS / ROWS_PER_BLOCK) * (B_ROWS / JCHUNK));          // 32*16 = 512
    sim_k<<<grid, 256, 0, stream>>>(ebf, labels, Sall, Spos, ctr, out);
}

// Round 15
// 111.459 us; speedup vs baseline: 1.3294x; 1.0817x over previous
//
#include <hip/hip_runtime.h>
#include <hip/hip_bf16.h>
#include <stdint.h>

#define B_ROWS 8192
#define DIM 256
#define JCHUNK 512
#define WPB 4   // waves per block
#define ROWS_PER_WAVE 64
#define ROWS_PER_BLOCK (WPB * ROWS_PER_WAVE)  // 256
#define NT (JCHUNK / 16)                      // 32 j-tiles per block
#define NTILES 4                              // A row-tiles per wave

typedef __bf16 bf16x8 __attribute__((ext_vector_type(8)));
typedef float f32x4 __attribute__((ext_vector_type(4)));

#if __has_builtin(__builtin_amdgcn_exp2f)
#define EXP2F(x) __builtin_amdgcn_exp2f(x)
#else
#define EXP2F(x) exp2f(x)
#endif

__device__ __forceinline__ unsigned short f2bf_rne(float f) {
    unsigned int u = __builtin_bit_cast(unsigned int, f);
    unsigned int r = (u + 0x7FFFu + ((u >> 16) & 1u)) >> 16;
    return (unsigned short)r;
}

// async global->LDS, 16B per lane; LDS dest is wave-uniform base + lane*16 (linear)
__device__ __forceinline__ void gld_lds16(const void* g, void* l) {
    __builtin_amdgcn_global_load_lds(
        (const __attribute__((address_space(1))) unsigned int*)g,
        (__attribute__((address_space(3))) unsigned int*)l, 16, 0, 0);
}

// ---------------- Kernel 1: L2-normalize rows -> bf16, zero accumulators + counter ----------------
__global__ __launch_bounds__(256) void normalize_k(const float* __restrict__ emb,
                                                   unsigned short* __restrict__ ebf,
                                                   float* __restrict__ Sall,
                                                   unsigned int* __restrict__ ctr) {
    const int idx = blockIdx.x * 256 + threadIdx.x;
    if (idx < 4096) {
        float4 z = {0.f, 0.f, 0.f, 0.f};
        reinterpret_cast<float4*>(Sall)[idx] = z;  // zeroes Sall+Spos (16384 floats)
    }
    if (idx == 0) *ctr = 0u;
    const int row = blockIdx.x * 4 + (threadIdx.x >> 6);
    const int lane = threadIdx.x & 63;  // 4 floats each covers DIM=256
    const float4 v = reinterpret_cast<const float4*>(emb + (size_t)row * DIM)[lane];
    float ss = v.x * v.x + v.y * v.y + v.z * v.z + v.w * v.w;
    #pragma unroll
    for (int off = 32; off; off >>= 1) ss += __shfl_xor(ss, off);
    const float scale = 1.0f / fmaxf(sqrtf(ss), 1e-12f);
    ushort4 o;
    o.x = f2bf_rne(v.x * scale);
    o.y = f2bf_rne(v.y * scale);
    o.z = f2bf_rne(v.z * scale);
    o.w = f2bf_rne(v.w * scale);
    reinterpret_cast<ushort4*>(ebf + (size_t)row * DIM)[lane] = o;
}

// ---------------- Kernel 2: fused sim + masked exp-sum + fence-free finalize (BATCHED) ----------------
// Main loop byte-identical to the proven 50.9us R10 kernel. R14 postmortem: the
// fence-free fused finalize was correct (absmax 0, no L2 storm) but its atomic
// RMW-reads were a serial latency chain -- 64 dependent ~500cyc round trips ~= 14us
// idle tail (MfmaUtil 19.8% == 25% x 51/64.7 confirmed the main loop unchanged).
// Fix: batch the RMW-reads 8-wide (16 independent atomics in flight per chunk),
// tail -> ~2us. Producer ordering unchanged: s_waitcnt vmcnt(0) before ctr bump
// (atomics complete at coherence point; no __threadfence = no wbl2/inv storm, R13).
__global__ __launch_bounds__(256, 2) void sim_k(const unsigned short* __restrict__ ebf,
                                                const int* __restrict__ labels,
                                                float* __restrict__ Sall,
                                                float* __restrict__ Spos,
                                                unsigned int* __restrict__ ctr,
                                                float* __restrict__ out) {
    // exp((dot-1)/T) = exp2((dot-1) * INV_T*log2e)
    constexpr float K2 = 14.285714285714286f * 1.4426950408889634f;  // 20.60993
    __shared__ __align__(16) unsigned char bufs[2][8192];            // 16 KB
    __shared__ int lds_lab[JCHUNK];
    __shared__ int lastblk;
    __shared__ float fsum[WPB];
    __shared__ int fcnt[WPB];

    const int tid  = threadIdx.x;
    const int wave = tid >> 6;
    const int lane = tid & 63;
    const int col  = lane & 15;
    const int quad = lane >> 4;
    const int lo   = lane & 31;
    const int hi   = lane >> 5;

    const int rowblk = blockIdx.x >> 4;            // 0..31
    const int jblk   = blockIdx.x & 15;            // 0..15
    const int i_base = rowblk * ROWS_PER_BLOCK + wave * ROWS_PER_WAVE;
    const int j0     = jblk * JCHUNK;

    // ---- Preload A-fragments (4 tiles x 8 K-steps) + row labels ----
    // lane L holds A[row = L&15][k = kk*32 + (L>>4)*8 + 0..7]
    bf16x8 afrag[NTILES][8];
    int li[NTILES][4];
    #pragma unroll
    for (int t = 0; t < NTILES; ++t) {
        const int arow = i_base + t * 16 + col;
        const uint4* ap = reinterpret_cast<const uint4*>(ebf) + (size_t)arow * 32 + quad;
        #pragma unroll
        for (int kk = 0; kk < 8; ++kk)
            afrag[t][kk] = __builtin_bit_cast(bf16x8, ap[kk * 4]);
        #pragma unroll
        for (int r = 0; r < 4; ++r)
            li[t][r] = labels[i_base + t * 16 + quad * 4 + r];
    }

    // ---- Per-lane pre-swizzled global source offsets (R6-proven) ----
    int voff[2];
    #pragma unroll
    for (int i = 0; i < 2; ++i) {
        const int r = 4 * wave + 2 * i + hi;
        voff[i] = r * 512 + ((lo ^ r) & 31) * 16;
    }
    const int ldst0 = wave * 2048;

    const char* gBase = reinterpret_cast<const char*>(ebf) + (size_t)j0 * 512;

    // ---- Prologue: labels -> LDS; stage tile 0 into bufs[0] ----
    lds_lab[tid] = labels[j0 + tid];
    lds_lab[256 + tid] = labels[j0 + 256 + tid];
    gld_lds16(gBase + voff[0], bufs[0] + ldst0);
    gld_lds16(gBase + voff[1], bufs[0] + ldst0 + 1024);
    __syncthreads();

    float s_all[NTILES][4] = {};
    float s_pos[NTILES][4] = {};
    f32x4 accA[NTILES], accB[NTILES];

    auto do_mfma = [&](f32x4* acc, const unsigned char* bufR) {
        #pragma unroll
        for (int t = 0; t < NTILES; ++t) acc[t] = (f32x4){0.f, 0.f, 0.f, 0.f};
        __builtin_amdgcn_s_setprio(1);
        #pragma unroll
        for (int kk = 0; kk < 8; ++kk) {
            const int c = kk * 4 + quad;
            const bf16x8 bfrag = *reinterpret_cast<const bf16x8*>(
                &bufR[col * 512 + ((c ^ col) & 31) * 16]);
            #pragma unroll
            for (int t = 0; t < NTILES; ++t)
                acc[t] = __builtin_amdgcn_mfma_f32_16x16x32_bf16(afrag[t][kk], bfrag, acc[t], 0, 0, 0);
        }
        __builtin_amdgcn_s_setprio(0);
    };

    auto do_epi = [&](const f32x4* acc, int jt) {
        const int lj = lds_lab[jt * 16 + col];
        const int jcol = j0 + jt * 16 + col;
        const int jt16 = j0 + jt * 16;
        const bool diag_possible = (jt16 < i_base + ROWS_PER_WAVE) && (i_base < jt16 + 16);
        if (!diag_possible) {
            #pragma unroll
            for (int t = 0; t < NTILES; ++t) {
                #pragma unroll
                for (int r = 0; r < 4; ++r) {
                    const float ex = EXP2F(fmaf(acc[t][r], K2, -K2));
                    s_all[t][r] += ex;
                    s_pos[t][r] += (lj == li[t][r]) ? ex : 0.0f;
                }
            }
        } else {
            #pragma unroll
            for (int t = 0; t < NTILES; ++t) {
                #pragma unroll
                for (int r = 0; r < 4; ++r) {
                    const int irow = i_base + t * 16 + quad * 4 + r;
                    const float ex = EXP2F(fmaf(acc[t][r], K2, -K2));
                    const bool valid = (jcol != irow);
                    const bool pos = valid && (lj == li[t][r]);
                    s_all[t][r] += valid ? ex : 0.0f;
                    s_pos[t][r] += pos ? ex : 0.0f;
                }
            }
        }
    };

    #pragma unroll 1
    for (int m = 0; m < NT / 2; ++m) {
        const int jt0 = 2 * m, jt1 = 2 * m + 1;

        // ---- phase jt0: read bufs[0], stage jt0+1 into bufs[1] ----
        {
            const char* gT = gBase + (size_t)(jt0 + 1) * 8192;   // jt0+1 <= 31 always
            gld_lds16(gT + voff[0], bufs[1] + ldst0);
            gld_lds16(gT + voff[1], bufs[1] + ldst0 + 1024);
        }
        do_mfma(accA, bufs[0]);
        if (m > 0) do_epi(accB, jt0 - 1);   // overlap: exp(jt0-1) under MFMA(jt0) drain
        __syncthreads();

        // ---- phase jt1: read bufs[1], stage jt1+1 into bufs[0] ----
        if (jt1 + 1 < NT) {
            const char* gT = gBase + (size_t)(jt1 + 1) * 8192;
            gld_lds16(gT + voff[0], bufs[0] + ldst0);
            gld_lds16(gT + voff[1], bufs[0] + ldst0 + 1024);
        }
        do_mfma(accB, bufs[1]);
        do_epi(accA, jt0);                  // overlap: exp(jt0) under MFMA(jt1) drain
        __syncthreads();
    }
    do_epi(accB, NT - 1);                   // tail epilogue

    // Reduce over the 16 column-lanes within each quad, then one atomic per row.
    #pragma unroll
    for (int t = 0; t < NTILES; ++t) {
        #pragma unroll
        for (int r = 0; r < 4; ++r) {
            float a = s_all[t][r];
            float pp = s_pos[t][r];
            #pragma unroll
            for (int off = 1; off < 16; off <<= 1) {
                a += __shfl_xor(a, off);
                pp += __shfl_xor(pp, off);
            }
            if (col == 0) {
                const int irow = i_base + t * 16 + quad * 4 + r;
                atomicAdd(&Sall[irow], a);
                atomicAdd(&Spos[irow], pp);
            }
        }
    }

    // ---- Fence-free fused finalize (batched RMW-reads) ----
    asm volatile("s_waitcnt vmcnt(0)" ::: "memory");  // this block's atomics complete
    __syncthreads();
    if (tid == 0) {
        const unsigned prev = atomicAdd(ctr, 1u);     // device-scope RMW
        lastblk = (prev == (unsigned)(gridDim.x - 1)) ? 1 : 0;
    }
    __syncthreads();
    if (lastblk) {
        float sum = 0.0f;
        int cnt = 0;
        // thread tid owns rows {tid + 256*j}; process in chunks of 8 with all 16
        // atomic RMW-reads issued before any consumption (latency hiding).
        #pragma unroll 1
        for (int c8 = 0; c8 < (B_ROWS / 256) / 8; ++c8) {
            float spv[8], sav[8];
            #pragma unroll
            for (int k = 0; k < 8; ++k) {
                const int i = tid + (c8 * 8 + k) * 256;
                spv[k] = atomicAdd(&Spos[i], 0.0f);   // RMW-read: coherent vs producers
                sav[k] = atomicAdd(&Sall[i], 0.0f);
            }
            #pragma unroll
            for (int k = 0; k < 8; ++k) {
                if (spv[k] > 0.0f) {
                    sum += __logf(__fdividef(sav[k], spv[k]));
                    ++cnt;
                }
            }
        }
        #pragma unroll
        for (int off = 32; off; off >>= 1) {
            sum += __shfl_xor(sum, off);
            cnt += __shfl_xor(cnt, off);
        }
        if (lane == 0) { fsum[wave] = sum; fcnt[wave] = cnt; }
        __syncthreads();
        if (tid == 0) {
            float s = 0.0f;
            int c = 0;
            #pragma unroll
            for (int w = 0; w < WPB; ++w) { s += fsum[w]; c += fcnt[w]; }
            out[0] = (c > 0) ? s / (float)c : 0.0f;
        }
    }
}

extern "C" void kernel_launch(void* const* d_in, const int* in_sizes, int n_in,
                              void* d_out, int out_size, void* d_ws, size_t ws_size,
                              hipStream_t stream) {
    const float* emb   = (const float*)d_in[0];
    const int* labels  = (const int*)d_in[1];
    float* out         = (float*)d_out;

    unsigned short* ebf = (unsigned short*)d_ws;                       // 4 MB bf16 normalized
    float* Sall = (float*)((char*)d_ws + (size_t)B_ROWS * DIM * 2);    // 32 KB
    float* Spos = Sall + B_ROWS;                                       // 32 KB
    unsigned int* ctr = (unsigned int*)(Spos + B_ROWS);                // 4 B

    normalize_k<<<B_ROWS / 4, 256, 0, stream>>>(emb, ebf, Sall, ctr);

    dim3 grid((B_ROWS / ROWS_PER_BLOCK) * (B_ROWS / JCHUNK));          // 32*16 = 512
    sim_k<<<grid, 256, 0, stream>>>(ebf, labels, Sall, Spos, ctr, out);
}

// Round 16
// 110.808 us; speedup vs baseline: 1.3372x; 1.0059x over previous
//
#include <hip/hip_runtime.h>
#include <hip/hip_bf16.h>
#include <stdint.h>

#define B_ROWS 8192
#define DIM 256
#define JCHUNK 512
#define WPB 4   // waves per block
#define ROWS_PER_WAVE 64
#define ROWS_PER_BLOCK (WPB * ROWS_PER_WAVE)  // 256
#define NT (JCHUNK / 16)                      // 32 j-tiles per block
#define NTILES 4                              // A row-tiles per wave

typedef __bf16 bf16x8 __attribute__((ext_vector_type(8)));
typedef float f32x4 __attribute__((ext_vector_type(4)));

#if __has_builtin(__builtin_amdgcn_exp2f)
#define EXP2F(x) __builtin_amdgcn_exp2f(x)
#else
#define EXP2F(x) exp2f(x)
#endif

__device__ __forceinline__ unsigned short f2bf_rne(float f) {
    unsigned int u = __builtin_bit_cast(unsigned int, f);
    unsigned int r = (u + 0x7FFFu + ((u >> 16) & 1u)) >> 16;
    return (unsigned short)r;
}

// async global->LDS, 16B per lane; LDS dest is wave-uniform base + lane*16 (linear)
__device__ __forceinline__ void gld_lds16(const void* g, void* l) {
    __builtin_amdgcn_global_load_lds(
        (const __attribute__((address_space(1))) unsigned int*)g,
        (__attribute__((address_space(3))) unsigned int*)l, 16, 0, 0);
}

// ---------------- Kernel 1: L2-normalize rows -> bf16, zero accumulators + counter ----------------
__global__ __launch_bounds__(256) void normalize_k(const float* __restrict__ emb,
                                                   unsigned short* __restrict__ ebf,
                                                   float* __restrict__ Sall,
                                                   unsigned int* __restrict__ ctr) {
    const int idx = blockIdx.x * 256 + threadIdx.x;
    if (idx < 4096) {
        float4 z = {0.f, 0.f, 0.f, 0.f};
        reinterpret_cast<float4*>(Sall)[idx] = z;  // zeroes Sall+Spos (16384 floats)
    }
    if (idx == 0) *ctr = 0u;
    const int row = blockIdx.x * 4 + (threadIdx.x >> 6);
    const int lane = threadIdx.x & 63;  // 4 floats each covers DIM=256
    const float4 v = reinterpret_cast<const float4*>(emb + (size_t)row * DIM)[lane];
    float ss = v.x * v.x + v.y * v.y + v.z * v.z + v.w * v.w;
    #pragma unroll
    for (int off = 32; off; off >>= 1) ss += __shfl_xor(ss, off);
    const float scale = 1.0f / fmaxf(sqrtf(ss), 1e-12f);
    ushort4 o;
    o.x = f2bf_rne(v.x * scale);
    o.y = f2bf_rne(v.y * scale);
    o.z = f2bf_rne(v.z * scale);
    o.w = f2bf_rne(v.w * scale);
    reinterpret_cast<ushort4*>(ebf + (size_t)row * DIM)[lane] = o;
}

// ---------------- Kernel 2: fused sim + masked exp-sum + fence-free finalize ----------------
// Main loop byte-identical to the proven 50.9us R10 kernel. Finalize evolution:
// R13: __threadfence -> L2 wbl2/inv storm, sim 89us. R14: serial RMW-reads, 14us
// tail. R15: batched RMW-reads, 6.6us tail (RMWs serialize per cache line + write
// back). R16: consumer uses __hip_atomic_load(RELAXED, AGENT) -- cache-bypassing
// plain loads that pipeline fully, no per-line RMW serialization, no writebacks.
// Ordering handoff unchanged: producers s_waitcnt vmcnt(0) (atomics complete at
// coherence point) before the ctr RMW; consumer's loads are control-dependent on
// observing ctr == grid-1. Agent-scope load coherence validated in R9/R11.
__global__ __launch_bounds__(256, 2) void sim_k(const unsigned short* __restrict__ ebf,
                                                const int* __restrict__ labels,
                                                float* __restrict__ Sall,
                                                float* __restrict__ Spos,
                                                unsigned int* __restrict__ ctr,
                                                float* __restrict__ out) {
    // exp((dot-1)/T) = exp2((dot-1) * INV_T*log2e)
    constexpr float K2 = 14.285714285714286f * 1.4426950408889634f;  // 20.60993
    __shared__ __align__(16) unsigned char bufs[2][8192];            // 16 KB
    __shared__ int lds_lab[JCHUNK];
    __shared__ int lastblk;
    __shared__ float fsum[WPB];
    __shared__ int fcnt[WPB];

    const int tid  = threadIdx.x;
    const int wave = tid >> 6;
    const int lane = tid & 63;
    const int col  = lane & 15;
    const int quad = lane >> 4;
    const int lo   = lane & 31;
    const int hi   = lane >> 5;

    const int rowblk = blockIdx.x >> 4;            // 0..31
    const int jblk   = blockIdx.x & 15;            // 0..15
    const int i_base = rowblk * ROWS_PER_BLOCK + wave * ROWS_PER_WAVE;
    const int j0     = jblk * JCHUNK;

    // ---- Preload A-fragments (4 tiles x 8 K-steps) + row labels ----
    // lane L holds A[row = L&15][k = kk*32 + (L>>4)*8 + 0..7]
    bf16x8 afrag[NTILES][8];
    int li[NTILES][4];
    #pragma unroll
    for (int t = 0; t < NTILES; ++t) {
        const int arow = i_base + t * 16 + col;
        const uint4* ap = reinterpret_cast<const uint4*>(ebf) + (size_t)arow * 32 + quad;
        #pragma unroll
        for (int kk = 0; kk < 8; ++kk)
            afrag[t][kk] = __builtin_bit_cast(bf16x8, ap[kk * 4]);
        #pragma unroll
        for (int r = 0; r < 4; ++r)
            li[t][r] = labels[i_base + t * 16 + quad * 4 + r];
    }

    // ---- Per-lane pre-swizzled global source offsets (R6-proven) ----
    int voff[2];
    #pragma unroll
    for (int i = 0; i < 2; ++i) {
        const int r = 4 * wave + 2 * i + hi;
        voff[i] = r * 512 + ((lo ^ r) & 31) * 16;
    }
    const int ldst0 = wave * 2048;

    const char* gBase = reinterpret_cast<const char*>(ebf) + (size_t)j0 * 512;

    // ---- Prologue: labels -> LDS; stage tile 0 into bufs[0] ----
    lds_lab[tid] = labels[j0 + tid];
    lds_lab[256 + tid] = labels[j0 + 256 + tid];
    gld_lds16(gBase + voff[0], bufs[0] + ldst0);
    gld_lds16(gBase + voff[1], bufs[0] + ldst0 + 1024);
    __syncthreads();

    float s_all[NTILES][4] = {};
    float s_pos[NTILES][4] = {};
    f32x4 accA[NTILES], accB[NTILES];

    auto do_mfma = [&](f32x4* acc, const unsigned char* bufR) {
        #pragma unroll
        for (int t = 0; t < NTILES; ++t) acc[t] = (f32x4){0.f, 0.f, 0.f, 0.f};
        __builtin_amdgcn_s_setprio(1);
        #pragma unroll
        for (int kk = 0; kk < 8; ++kk) {
            const int c = kk * 4 + quad;
            const bf16x8 bfrag = *reinterpret_cast<const bf16x8*>(
                &bufR[col * 512 + ((c ^ col) & 31) * 16]);
            #pragma unroll
            for (int t = 0; t < NTILES; ++t)
                acc[t] = __builtin_amdgcn_mfma_f32_16x16x32_bf16(afrag[t][kk], bfrag, acc[t], 0, 0, 0);
        }
        __builtin_amdgcn_s_setprio(0);
    };

    auto do_epi = [&](const f32x4* acc, int jt) {
        const int lj = lds_lab[jt * 16 + col];
        const int jcol = j0 + jt * 16 + col;
        const int jt16 = j0 + jt * 16;
        const bool diag_possible = (jt16 < i_base + ROWS_PER_WAVE) && (i_base < jt16 + 16);
        if (!diag_possible) {
            #pragma unroll
            for (int t = 0; t < NTILES; ++t) {
                #pragma unroll
                for (int r = 0; r < 4; ++r) {
                    const float ex = EXP2F(fmaf(acc[t][r], K2, -K2));
                    s_all[t][r] += ex;
                    s_pos[t][r] += (lj == li[t][r]) ? ex : 0.0f;
                }
            }
        } else {
            #pragma unroll
            for (int t = 0; t < NTILES; ++t) {
                #pragma unroll
                for (int r = 0; r < 4; ++r) {
                    const int irow = i_base + t * 16 + quad * 4 + r;
                    const float ex = EXP2F(fmaf(acc[t][r], K2, -K2));
                    const bool valid = (jcol != irow);
                    const bool pos = valid && (lj == li[t][r]);
                    s_all[t][r] += valid ? ex : 0.0f;
                    s_pos[t][r] += pos ? ex : 0.0f;
                }
            }
        }
    };

    #pragma unroll 1
    for (int m = 0; m < NT / 2; ++m) {
        const int jt0 = 2 * m, jt1 = 2 * m + 1;

        // ---- phase jt0: read bufs[0], stage jt0+1 into bufs[1] ----
        {
            const char* gT = gBase + (size_t)(jt0 + 1) * 8192;   // jt0+1 <= 31 always
            gld_lds16(gT + voff[0], bufs[1] + ldst0);
            gld_lds16(gT + voff[1], bufs[1] + ldst0 + 1024);
        }
        do_mfma(accA, bufs[0]);
        if (m > 0) do_epi(accB, jt0 - 1);   // overlap: exp(jt0-1) under MFMA(jt0) drain
        __syncthreads();

        // ---- phase jt1: read bufs[1], stage jt1+1 into bufs[0] ----
        if (jt1 + 1 < NT) {
            const char* gT = gBase + (size_t)(jt1 + 1) * 8192;
            gld_lds16(gT + voff[0], bufs[0] + ldst0);
            gld_lds16(gT + voff[1], bufs[0] + ldst0 + 1024);
        }
        do_mfma(accB, bufs[1]);
        do_epi(accA, jt0);                  // overlap: exp(jt0) under MFMA(jt1) drain
        __syncthreads();
    }
    do_epi(accB, NT - 1);                   // tail epilogue

    // Reduce over the 16 column-lanes within each quad, then one atomic per row.
    #pragma unroll
    for (int t = 0; t < NTILES; ++t) {
        #pragma unroll
        for (int r = 0; r < 4; ++r) {
            float a = s_all[t][r];
            float pp = s_pos[t][r];
            #pragma unroll
            for (int off = 1; off < 16; off <<= 1) {
                a += __shfl_xor(a, off);
                pp += __shfl_xor(pp, off);
            }
            if (col == 0) {
                const int irow = i_base + t * 16 + quad * 4 + r;
                atomicAdd(&Sall[irow], a);
                atomicAdd(&Spos[irow], pp);
            }
        }
    }

    // ---- Fence-free fused finalize (batched agent-scope loads) ----
    asm volatile("s_waitcnt vmcnt(0)" ::: "memory");  // this block's atomics complete
    __syncthreads();
    if (tid == 0) {
        const unsigned prev = atomicAdd(ctr, 1u);     // device-scope RMW
        lastblk = (prev == (unsigned)(gridDim.x - 1)) ? 1 : 0;
    }
    __syncthreads();
    if (lastblk) {
        float sum = 0.0f;
        int cnt = 0;
        // thread tid owns rows {tid + 256*j}; chunks of 8 with all 16 cache-
        // bypassing loads issued before any consumption (fully pipelined).
        #pragma unroll 1
        for (int c8 = 0; c8 < (B_ROWS / 256) / 8; ++c8) {
            float spv[8], sav[8];
            #pragma unroll
            for (int k = 0; k < 8; ++k) {
                const int i = tid + (c8 * 8 + k) * 256;
                spv[k] = __hip_atomic_load(&Spos[i], __ATOMIC_RELAXED, __HIP_MEMORY_SCOPE_AGENT);
                sav[k] = __hip_atomic_load(&Sall[i], __ATOMIC_RELAXED, __HIP_MEMORY_SCOPE_AGENT);
            }
            #pragma unroll
            for (int k = 0; k < 8; ++k) {
                if (spv[k] > 0.0f) {
                    sum += __logf(__fdividef(sav[k], spv[k]));
                    ++cnt;
                }
            }
        }
        #pragma unroll
        for (int off = 32; off; off >>= 1) {
            sum += __shfl_xor(sum, off);
            cnt += __shfl_xor(cnt, off);
        }
        if (lane == 0) { fsum[wave] = sum; fcnt[wave] = cnt; }
        __syncthreads();
        if (tid == 0) {
            float s = 0.0f;
            int c = 0;
            #pragma unroll
            for (int w = 0; w < WPB; ++w) { s += fsum[w]; c += fcnt[w]; }
            out[0] = (c > 0) ? s / (float)c : 0.0f;
        }
    }
}

extern "C" void kernel_launch(void* const* d_in, const int* in_sizes, int n_in,
                              void* d_out, int out_size, void* d_ws, size_t ws_size,
                              hipStream_t stream) {
    const float* emb   = (const float*)d_in[0];
    const int* labels  = (const int*)d_in[1];
    float* out         = (float*)d_out;

    unsigned short* ebf = (unsigned short*)d_ws;                       // 4 MB bf16 normalized
    float* Sall = (float*)((char*)d_ws + (size_t)B_ROWS * DIM * 2);    // 32 KB
    float* Spos = Sall + B_ROWS;                                       // 32 KB
    unsigned int* ctr = (unsigned int*)(Spos + B_ROWS);                // 4 B

    normalize_k<<<B_ROWS / 4, 256, 0, stream>>>(emb, ebf, Sall, ctr);

    dim3 grid((B_ROWS / ROWS_PER_BLOCK) * (B_ROWS / JCHUNK));          // 32*16 = 512
    sim_k<<<grid, 256, 0, stream>>>(ebf, labels, Sall, Spos, ctr, out);
}